// Round 3
// baseline (3861.000 us; speedup 1.0000x reference)
//
#include <hip/hip_runtime.h>
#include <hip/hip_bf16.h>

typedef __hip_bfloat16 bf16;

#define N_USERS 80000
#define N_ITEMS 20000
#define NTOT    100000
#define NEDGE   1600000
#define DDIM    128
#define NLAY    3
#define KHOP    3
#define NB      4096
#define SCAN_BS 1024

__global__ void beta_kernel(const float* __restrict__ alphas, float* __restrict__ beta) {
    if (threadIdx.x == 0 && blockIdx.x == 0) {
        for (int k = 0; k < NLAY; ++k) {
            float a[KHOP];
            float m = -1e30f;
            for (int i = 0; i < KHOP; ++i) { a[i] = alphas[k*KHOP+i]; m = fmaxf(m, a[i]); }
            float s = 0.f;
            for (int i = 0; i < KHOP; ++i) { a[i] = expf(a[i] - m); s += a[i]; }
            for (int i = 0; i < KHOP; ++i) beta[k*KHOP+i] = a[i] / s;
        }
    }
}

__global__ void build_ego_kernel(const float* __restrict__ feat, const float* __restrict__ user_emb,
                                 const float* __restrict__ item_emb1, const float* __restrict__ item_emb2,
                                 bf16* __restrict__ ego) {
    int i = blockIdx.x * 256 + threadIdx.x;   // exactly NTOT*DDIM threads
    int n = i >> 7, d = i & 127;
    float v;
    if (n < N_USERS) {
        v = (d < 64) ? user_emb[n*64 + d] : feat[n*64 + d - 64];
    } else {
        int m = n - N_USERS;
        v = (d < 64) ? item_emb1[m*64 + d] : item_emb2[m*64 + d - 64];
    }
    ego[i] = __float2bfloat16(v);
}

__global__ void zero_kernel(int* __restrict__ p, int n) {
    int i = blockIdx.x * 256 + threadIdx.x;
    if (i < n) p[i] = 0;
}

__global__ void hist_kernel(const int* __restrict__ er, int* __restrict__ counts) {
    int i = blockIdx.x * 256 + threadIdx.x;
    if (i < NEDGE) atomicAdd(&counts[er[i]], 1);
}

__global__ void scan1_kernel(const int* __restrict__ counts, int* __restrict__ rowptr,
                             int* __restrict__ bsums, int n) {
    __shared__ int sm[SCAN_BS];
    int i = blockIdx.x * SCAN_BS + threadIdx.x;
    int v = (i < n) ? counts[i] : 0;
    sm[threadIdx.x] = v;
    __syncthreads();
    for (int off = 1; off < SCAN_BS; off <<= 1) {
        int t = (threadIdx.x >= off) ? sm[threadIdx.x - off] : 0;
        __syncthreads();
        sm[threadIdx.x] += t;
        __syncthreads();
    }
    if (i < n) rowptr[i] = sm[threadIdx.x] - v;  // exclusive
    if (threadIdx.x == SCAN_BS - 1) bsums[blockIdx.x] = sm[SCAN_BS - 1];
}

__global__ void scan2_kernel(int* __restrict__ bsums, int nb) {
    if (threadIdx.x == 0 && blockIdx.x == 0) {
        int acc = 0;
        for (int b = 0; b < nb; ++b) { int t = bsums[b]; bsums[b] = acc; acc += t; }
    }
}

__global__ void scan3_kernel(int* __restrict__ rowptr, const int* __restrict__ bsums, int n) {
    int i = blockIdx.x * SCAN_BS + threadIdx.x;
    if (i < n) rowptr[i] += bsums[blockIdx.x];
    if (blockIdx.x == 0 && threadIdx.x == 0) rowptr[n] = NEDGE;
}

__global__ void copy_kernel(const int* __restrict__ src, int* __restrict__ dst, int n) {
    int i = blockIdx.x * 256 + threadIdx.x;
    if (i < n) dst[i] = src[i];
}

__global__ void scatter_kernel(const int* __restrict__ er, const int* __restrict__ ec,
                               const float* __restrict__ ev, int* __restrict__ counters,
                               int* __restrict__ csr_col, float* __restrict__ csr_val) {
    int i = blockIdx.x * 256 + threadIdx.x;
    if (i < NEDGE) {
        int r = er[i];
        int p = atomicAdd(&counters[r], 1);
        csr_col[p] = ec[i];
        csr_val[p] = ev[i];
    }
}

// one row per 128 threads; 2 rows per 256-thread block
__global__ void spmm_kernel(const int* __restrict__ rowptr, const int* __restrict__ col,
                            const float* __restrict__ val, const bf16* __restrict__ X,
                            bf16* __restrict__ Y, float* __restrict__ side,
                            const float* __restrict__ betaArr, int betaIdx, int initSide) {
    int tid = threadIdx.x;
    int r = blockIdx.x * 2 + (tid >> 7);
    int c = tid & 127;
    int s = rowptr[r], e = rowptr[r + 1];
    float acc = 0.f;
    for (int j = s; j < e; ++j) {
        acc = fmaf(val[j], __bfloat162float(X[(size_t)col[j] * DDIM + c]), acc);
    }
    size_t oi = (size_t)r * DDIM + c;
    Y[oi] = __float2bfloat16(acc);
    float b = betaArr[betaIdx];
    float o = b * acc;
    if (initSide) side[oi] = o;
    else side[oi] += o;
}

__global__ __launch_bounds__(256) void layer_kernel(
    const bf16* __restrict__ ego, const float* __restrict__ side,
    const float* __restrict__ Wgc, const float* __restrict__ bgc,
    const float* __restrict__ Wbi, const float* __restrict__ bbi,
    bf16* __restrict__ ego_out, float* __restrict__ normbuf) {
    __shared__ bf16 sWgc[DDIM * DDIM];   // 32 KB
    __shared__ bf16 sWbi[DDIM * DDIM];   // 32 KB
    __shared__ float sSide[2 * DDIM];
    __shared__ float sEgo[2 * DDIM];
    __shared__ float partials[4];
    int tid = threadIdx.x;
    for (int i = tid; i < DDIM * DDIM; i += 256) {
        sWgc[i] = __float2bfloat16(Wgc[i]);
        sWbi[i] = __float2bfloat16(Wbi[i]);
    }
    __syncthreads();
    int c = tid & 127;
    int rl = tid >> 7;
    float bg = bgc[c];
    float bb = bbi[c];
    for (int base = blockIdx.x * 2; base < NTOT; base += gridDim.x * 2) {
        sSide[tid] = side[(size_t)base * DDIM + tid];
        sEgo[tid]  = __bfloat162float(ego[(size_t)base * DDIM + tid]);
        __syncthreads();
        const float* sd = &sSide[rl * DDIM];
        const float* eg = &sEgo[rl * DDIM];
        float accg = bg, accb = bb;
        #pragma unroll 8
        for (int j = 0; j < DDIM; ++j) {
            float s = sd[j];
            accg = fmaf(s, __bfloat162float(sWgc[j * DDIM + c]), accg);
            accb = fmaf(s * eg[j], __bfloat162float(sWbi[j * DDIM + c]), accb);
        }
        float v = (accg > 0.f ? accg : 0.2f * accg) + accb;
        float sq = v * v;
        #pragma unroll
        for (int o = 1; o < 64; o <<= 1) sq += __shfl_xor(sq, o, 64);
        if ((tid & 63) == 0) partials[tid >> 6] = sq;
        __syncthreads();
        float nrm = sqrtf(partials[rl * 2] + partials[rl * 2 + 1]);
        float rn = 1.0f / fmaxf(nrm, 1e-12f);
        size_t oi = (size_t)base * DDIM + tid;
        ego_out[oi] = __float2bfloat16(v);
        normbuf[oi] = v * rn;      // in-place over side (dead after this read)
        __syncthreads();
    }
}

// slot 0: gather raw ego rows EXACTLY from the fp32 inputs
__global__ void gather_ego_kernel(const float* __restrict__ feat, const float* __restrict__ user_emb,
                                  const float* __restrict__ item_emb1, const float* __restrict__ item_emb2,
                                  const int* __restrict__ users, const int* __restrict__ pos,
                                  const int* __restrict__ neg, float* __restrict__ out) {
    int i = blockIdx.x * 256 + threadIdx.x;  // exactly 3*NB*128 threads
    int which = i / (NB * DDIM);
    int rem = i - which * (NB * DDIM);
    int b = rem >> 7, d = rem & 127;
    float v;
    if (which == 0) {
        int u = users[b];
        v = (d < 64) ? user_emb[u*64 + d] : feat[u*64 + d - 64];
    } else {
        int m = (which == 1) ? pos[b] : neg[b];
        v = (d < 64) ? item_emb1[m*64 + d] : item_emb2[m*64 + d - 64];
    }
    out[(size_t)which * NB * 512 + (size_t)b * 512 + d] = v;
}

// slots 1..3: gather the 128-wide normalized slice from fp32 normbuf
__global__ void gather_slice_kernel(const float* __restrict__ src, const int* __restrict__ users,
                                    const int* __restrict__ pos, const int* __restrict__ neg,
                                    float* __restrict__ out, int slot) {
    int i = blockIdx.x * 256 + threadIdx.x;  // exactly 3*NB*128 threads
    int which = i / (NB * DDIM);
    int rem = i - which * (NB * DDIM);
    int b = rem >> 7, c = rem & 127;
    int row;
    if (which == 0)      row = users[b];
    else if (which == 1) row = N_USERS + pos[b];
    else                 row = N_USERS + neg[b];
    out[(size_t)which * NB * 512 + (size_t)b * 512 + slot * 128 + c] =
        src[(size_t)row * DDIM + c];
}

extern "C" void kernel_launch(void* const* d_in, const int* in_sizes, int n_in,
                              void* d_out, int out_size, void* d_ws, size_t ws_size,
                              hipStream_t stream) {
    (void)in_sizes; (void)n_in; (void)out_size; (void)ws_size;
    const int*   edge_row  = (const int*)  d_in[0];
    const int*   edge_col  = (const int*)  d_in[1];
    const float* edge_val  = (const float*)d_in[2];
    const float* feat      = (const float*)d_in[3];
    const float* user_emb  = (const float*)d_in[4];
    const float* item_emb1 = (const float*)d_in[5];
    const float* item_emb2 = (const float*)d_in[6];
    const float* alphas    = (const float*)d_in[7];
    const float* W_gc      = (const float*)d_in[8];
    const float* b_gc      = (const float*)d_in[9];
    const float* W_bi      = (const float*)d_in[10];
    const float* b_bi      = (const float*)d_in[11];
    const int*   users     = (const int*)  d_in[12];
    const int*   pos_items = (const int*)  d_in[13];
    const int*   neg_items = (const int*)  d_in[14];
    float* out = (float*)d_out;

    char* ws = (char*)d_ws;
    size_t off = 0;
    auto alloc = [&](size_t bytes) -> char* {
        char* p = ws + off;
        off = (off + bytes + 255) & ~(size_t)255;
        return p;
    };
    // total ~142 MB (round 2 ran at ~139 MB without faulting)
    bf16*  ego      = (bf16*) alloc((size_t)NTOT * DDIM * 2);   // 25.6 MB
    bf16*  cur      = (bf16*) alloc((size_t)NTOT * DDIM * 2);   // 25.6 MB
    bf16*  nxt      = (bf16*) alloc((size_t)NTOT * DDIM * 2);   // 25.6 MB
    float* side     = (float*)alloc((size_t)NTOT * DDIM * 4);   // 51.2 MB (also norm output)
    int*   rowptr   = (int*)  alloc((size_t)(NTOT + 1) * 4);
    int*   counts   = (int*)  alloc((size_t)NTOT * 4);
    int*   counters = (int*)  alloc((size_t)NTOT * 4);
    int*   bsums    = (int*)  alloc(4096);
    int*   csr_col  = (int*)  alloc((size_t)NEDGE * 4);         // 6.4 MB
    float* csr_val  = (float*)alloc((size_t)NEDGE * 4);         // 6.4 MB
    float* beta     = (float*)alloc(256);

    beta_kernel<<<1, 64, 0, stream>>>(alphas, beta);
    build_ego_kernel<<<(NTOT * DDIM) / 256, 256, 0, stream>>>(feat, user_emb, item_emb1, item_emb2, ego);

    zero_kernel<<<(NTOT + 255) / 256, 256, 0, stream>>>(counts, NTOT);
    hist_kernel<<<NEDGE / 256, 256, 0, stream>>>(edge_row, counts);
    int nblk = (NTOT + SCAN_BS - 1) / SCAN_BS;
    scan1_kernel<<<nblk, SCAN_BS, 0, stream>>>(counts, rowptr, bsums, NTOT);
    scan2_kernel<<<1, 64, 0, stream>>>(bsums, nblk);
    scan3_kernel<<<nblk, SCAN_BS, 0, stream>>>(rowptr, bsums, NTOT);
    copy_kernel<<<(NTOT + 255) / 256, 256, 0, stream>>>(rowptr, counters, NTOT);
    scatter_kernel<<<NEDGE / 256, 256, 0, stream>>>(edge_row, edge_col, edge_val, counters, csr_col, csr_val);

    // slot 0 of the output: raw ego rows, exact fp32
    gather_ego_kernel<<<(3 * NB * DDIM) / 256, 256, 0, stream>>>(feat, user_emb, item_emb1, item_emb2,
                                                                 users, pos_items, neg_items, out);

    for (int k = 0; k < NLAY; ++k) {
        spmm_kernel<<<NTOT / 2, 256, 0, stream>>>(rowptr, csr_col, csr_val, ego, cur, side, beta, k * KHOP + 0, 1);
        spmm_kernel<<<NTOT / 2, 256, 0, stream>>>(rowptr, csr_col, csr_val, cur, nxt, side, beta, k * KHOP + 1, 0);
        spmm_kernel<<<NTOT / 2, 256, 0, stream>>>(rowptr, csr_col, csr_val, nxt, cur, side, beta, k * KHOP + 2, 0);
        layer_kernel<<<512, 256, 0, stream>>>(ego, side,
                                              W_gc + (size_t)k * DDIM * DDIM, b_gc + (size_t)k * DDIM,
                                              W_bi + (size_t)k * DDIM * DDIM, b_bi + (size_t)k * DDIM,
                                              ego, side);
        gather_slice_kernel<<<(3 * NB * DDIM) / 256, 256, 0, stream>>>(side, users, pos_items, neg_items, out, k + 1);
    }
}

// Round 4
// 1111.688 us; speedup vs baseline: 3.4731x; 3.4731x over previous
//
#include <hip/hip_runtime.h>
#include <hip/hip_bf16.h>

typedef __hip_bfloat16 hbf16;
typedef unsigned short u16;
typedef __bf16 bf16x8 __attribute__((ext_vector_type(8)));
typedef float f32x4 __attribute__((ext_vector_type(4)));

#define N_USERS 80000
#define N_ITEMS 20000
#define NTOT    100000
#define NEDGE   1600000
#define DDIM    128
#define NLAY    3
#define KHOP    3
#define NB      4096
#define SCAN_BS 1024
#define LBM     128   // rows per layer block

__device__ inline u16 f2bfu(float f) { __bf16 h = (__bf16)f; return __builtin_bit_cast(u16, h); }

__global__ void beta_kernel(const float* __restrict__ alphas, float* __restrict__ beta) {
    if (threadIdx.x == 0 && blockIdx.x == 0) {
        for (int k = 0; k < NLAY; ++k) {
            float a[KHOP];
            float m = -1e30f;
            for (int i = 0; i < KHOP; ++i) { a[i] = alphas[k*KHOP+i]; m = fmaxf(m, a[i]); }
            float s = 0.f;
            for (int i = 0; i < KHOP; ++i) { a[i] = expf(a[i] - m); s += a[i]; }
            for (int i = 0; i < KHOP; ++i) beta[k*KHOP+i] = a[i] / s;
        }
    }
}

__global__ void build_ego_kernel(const float* __restrict__ feat, const float* __restrict__ user_emb,
                                 const float* __restrict__ item_emb1, const float* __restrict__ item_emb2,
                                 u16* __restrict__ ego) {
    int i = blockIdx.x * 256 + threadIdx.x;   // exactly NTOT*DDIM threads
    int n = i >> 7, d = i & 127;
    float v;
    if (n < N_USERS) {
        v = (d < 64) ? user_emb[n*64 + d] : feat[n*64 + d - 64];
    } else {
        int m = n - N_USERS;
        v = (d < 64) ? item_emb1[m*64 + d] : item_emb2[m*64 + d - 64];
    }
    ego[i] = f2bfu(v);
}

// transpose 6 128x128 fp32 matrices into bf16 (WT[n][k] = W[k][n])
__global__ void transpose_w_kernel(const float* __restrict__ Wgc, const float* __restrict__ Wbi,
                                   u16* __restrict__ WTgc, u16* __restrict__ WTbi) {
    __shared__ float t[32][33];
    int z = blockIdx.z;
    const float* W = (z < 3) ? (Wgc + (size_t)z * 16384) : (Wbi + (size_t)(z - 3) * 16384);
    u16* WT = (z < 3) ? (WTgc + (size_t)z * 16384) : (WTbi + (size_t)(z - 3) * 16384);
    int r0 = blockIdx.y * 32, c0 = blockIdx.x * 32;
    for (int i = threadIdx.y; i < 32; i += 8)
        t[i][threadIdx.x] = W[(size_t)(r0 + i) * 128 + c0 + threadIdx.x];
    __syncthreads();
    for (int i = threadIdx.y; i < 32; i += 8)
        WT[(size_t)(c0 + i) * 128 + r0 + threadIdx.x] = f2bfu(t[threadIdx.x][i]);
}

__global__ void zero_kernel(int* __restrict__ p, int n) {
    int i = blockIdx.x * 256 + threadIdx.x;
    if (i < n) p[i] = 0;
}

__global__ void hist_kernel(const int* __restrict__ er, int* __restrict__ counts) {
    int i = blockIdx.x * 256 + threadIdx.x;
    if (i < NEDGE) atomicAdd(&counts[er[i]], 1);
}

__global__ void scan1_kernel(const int* __restrict__ counts, int* __restrict__ rowptr,
                             int* __restrict__ bsums, int n) {
    __shared__ int sm[SCAN_BS];
    int i = blockIdx.x * SCAN_BS + threadIdx.x;
    int v = (i < n) ? counts[i] : 0;
    sm[threadIdx.x] = v;
    __syncthreads();
    for (int off = 1; off < SCAN_BS; off <<= 1) {
        int t = (threadIdx.x >= off) ? sm[threadIdx.x - off] : 0;
        __syncthreads();
        sm[threadIdx.x] += t;
        __syncthreads();
    }
    if (i < n) rowptr[i] = sm[threadIdx.x] - v;  // exclusive
    if (threadIdx.x == SCAN_BS - 1) bsums[blockIdx.x] = sm[SCAN_BS - 1];
}

__global__ void scan2_kernel(int* __restrict__ bsums, int nb) {
    if (threadIdx.x == 0 && blockIdx.x == 0) {
        int acc = 0;
        for (int b = 0; b < nb; ++b) { int t = bsums[b]; bsums[b] = acc; acc += t; }
    }
}

__global__ void scan3_kernel(int* __restrict__ rowptr, const int* __restrict__ bsums, int n) {
    int i = blockIdx.x * SCAN_BS + threadIdx.x;
    if (i < n) rowptr[i] += bsums[blockIdx.x];
    if (blockIdx.x == 0 && threadIdx.x == 0) rowptr[n] = NEDGE;
}

__global__ void copy_kernel(const int* __restrict__ src, int* __restrict__ dst, int n) {
    int i = blockIdx.x * 256 + threadIdx.x;
    if (i < n) dst[i] = src[i];
}

__global__ void scatter_kernel(const int* __restrict__ er, const int* __restrict__ ec,
                               const float* __restrict__ ev, int* __restrict__ counters,
                               int* __restrict__ csr_col, float* __restrict__ csr_val) {
    int i = blockIdx.x * 256 + threadIdx.x;
    if (i < NEDGE) {
        int r = er[i];
        int p = atomicAdd(&counters[r], 1);
        csr_col[p] = ec[i];
        csr_val[p] = ev[i];
    }
}

// 16 lanes per row, 16 rows per 256-thread block; each lane owns 8 columns (16B loads)
__global__ __launch_bounds__(256) void spmm_kernel(
    const int* __restrict__ rowptr, const int* __restrict__ col,
    const float* __restrict__ val, const u16* __restrict__ X,
    u16* __restrict__ Y, float* __restrict__ side,
    const float* __restrict__ betaArr, int betaIdx, int initSide) {
    int tid = threadIdx.x;
    int r = blockIdx.x * 16 + (tid >> 4);
    int lane = tid & 15;
    int s = rowptr[r], e = rowptr[r + 1];
    float acc[8];
    #pragma unroll
    for (int i = 0; i < 8; ++i) acc[i] = 0.f;
    const u16* xb = X + lane * 8;
    for (int j = s; j < e; ++j) {
        int c = col[j];
        float v = val[j];
        bf16x8 x = *reinterpret_cast<const bf16x8*>(xb + (size_t)c * DDIM);
        #pragma unroll
        for (int i = 0; i < 8; ++i) acc[i] = fmaf(v, (float)x[i], acc[i]);
    }
    size_t oi = (size_t)r * DDIM + lane * 8;
    bf16x8 y;
    #pragma unroll
    for (int i = 0; i < 8; ++i) y[i] = (__bf16)acc[i];
    *reinterpret_cast<bf16x8*>(Y + oi) = y;
    float b = betaArr[betaIdx];
    float4 s0, s1;
    if (initSide) {
        s0 = make_float4(b*acc[0], b*acc[1], b*acc[2], b*acc[3]);
        s1 = make_float4(b*acc[4], b*acc[5], b*acc[6], b*acc[7]);
    } else {
        float4 o0 = *reinterpret_cast<const float4*>(side + oi);
        float4 o1 = *reinterpret_cast<const float4*>(side + oi + 4);
        s0 = make_float4(o0.x + b*acc[0], o0.y + b*acc[1], o0.z + b*acc[2], o0.w + b*acc[3]);
        s1 = make_float4(o1.x + b*acc[4], o1.y + b*acc[5], o1.z + b*acc[6], o1.w + b*acc[7]);
    }
    *reinterpret_cast<float4*>(side + oi) = s0;
    *reinterpret_cast<float4*>(side + oi + 4) = s1;
}

// MFMA layer: 512 threads = 8 waves, 128 rows/block, each wave a 16-row strip.
// LDS: As(16KBx2=32KB) Ab(32KB) WTgc(32KB) WTbi(32KB) = 128KB, XOR-swizzled.
__global__ __launch_bounds__(512) void layer_kernel(
    const u16* __restrict__ ego, const float* __restrict__ side,
    const u16* __restrict__ wtgc, const u16* __restrict__ wtbi,
    const float* __restrict__ bgc, const float* __restrict__ bbi,
    u16* __restrict__ ego_out, float* __restrict__ normbuf) {
    __shared__ __align__(16) unsigned char smem[131072];
    const int AS = 0, AB = 32768, WG = 65536, WB = 98304;
    int tid = threadIdx.x;
    int base = blockIdx.x * LBM;

    // stage As = bf16(side), Ab = bf16(side*ego), rows of 256B, byte ^= (row&7)<<4
    {
        int row = tid >> 2, q = tid & 3;
        int grow = base + row;
        bool ok = grow < NTOT;
        const float* srow = side + (size_t)grow * DDIM + q * 32;
        const u16*   erow = ego  + (size_t)grow * DDIM + q * 32;
        int sw = (row & 7) << 4;
        #pragma unroll
        for (int cg = 0; cg < 4; ++cg) {
            bf16x8 pa, pb;
            if (ok) {
                float4 f0 = *reinterpret_cast<const float4*>(srow + cg * 8);
                float4 f1 = *reinterpret_cast<const float4*>(srow + cg * 8 + 4);
                bf16x8 ev = *reinterpret_cast<const bf16x8*>(erow + cg * 8);
                float sv[8] = {f0.x, f0.y, f0.z, f0.w, f1.x, f1.y, f1.z, f1.w};
                #pragma unroll
                for (int i = 0; i < 8; ++i) {
                    pa[i] = (__bf16)sv[i];
                    pb[i] = (__bf16)(sv[i] * (float)ev[i]);
                }
            } else {
                #pragma unroll
                for (int i = 0; i < 8; ++i) { pa[i] = (__bf16)0.f; pb[i] = (__bf16)0.f; }
            }
            int kb = q * 64 + cg * 16;
            *reinterpret_cast<bf16x8*>(&smem[AS + row * 256 + (kb ^ sw)]) = pa;
            *reinterpret_cast<bf16x8*>(&smem[AB + row * 256 + (kb ^ sw)]) = pb;
        }
    }
    // stage pre-transposed W (bf16): WT[n][k], same swizzle
    #pragma unroll
    for (int p = 0; p < 4; ++p) {
        int slot = tid + p * 512;            // 2048 16B slots
        int n = slot >> 4, ks = slot & 15;
        uint4 g  = *reinterpret_cast<const uint4*>(wtgc + n * DDIM + ks * 8);
        uint4 bq = *reinterpret_cast<const uint4*>(wtbi + n * DDIM + ks * 8);
        int addr = n * 256 + ((ks * 16) ^ ((n & 7) << 4));
        *reinterpret_cast<uint4*>(&smem[WG + addr]) = g;
        *reinterpret_cast<uint4*>(&smem[WB + addr]) = bq;
    }
    __syncthreads();

    int l = tid & 63, w = tid >> 6;
    int m = l & 15, g16 = l >> 4;
    int sw = (m & 7) << 4;
    int arow = (w * 16 + m) * 256;
    f32x4 accg[8], accb[8];
    #pragma unroll
    for (int nt = 0; nt < 8; ++nt) {
        accg[nt] = (f32x4){0.f, 0.f, 0.f, 0.f};
        accb[nt] = (f32x4){0.f, 0.f, 0.f, 0.f};
    }
    #pragma unroll
    for (int kk = 0; kk < 4; ++kk) {
        int ka = (kk * 64 + g16 * 16) ^ sw;
        bf16x8 as = *reinterpret_cast<const bf16x8*>(&smem[AS + arow + ka]);
        bf16x8 ab = *reinterpret_cast<const bf16x8*>(&smem[AB + arow + ka]);
        #pragma unroll
        for (int nt = 0; nt < 8; ++nt) {
            int na = (nt * 16 + m) * 256 + ka;
            bf16x8 bg = *reinterpret_cast<const bf16x8*>(&smem[WG + na]);
            accg[nt] = __builtin_amdgcn_mfma_f32_16x16x32_bf16(as, bg, accg[nt], 0, 0, 0);
            bf16x8 bb = *reinterpret_cast<const bf16x8*>(&smem[WB + na]);
            accb[nt] = __builtin_amdgcn_mfma_f32_16x16x32_bf16(ab, bb, accb[nt], 0, 0, 0);
        }
    }
    // epilogue: bias + leaky + bilinear add, row-norm via 16-lane shfl reduce
    float bgv[8], bbv[8];
    #pragma unroll
    for (int nt = 0; nt < 8; ++nt) { bgv[nt] = bgc[nt * 16 + m]; bbv[nt] = bbi[nt * 16 + m]; }
    float vv[8][4];
    float ss[4] = {0.f, 0.f, 0.f, 0.f};
    #pragma unroll
    for (int nt = 0; nt < 8; ++nt) {
        #pragma unroll
        for (int rr = 0; rr < 4; ++rr) {
            float se = accg[nt][rr] + bgv[nt];
            float be = accb[nt][rr] + bbv[nt];
            float v = (se > 0.f ? se : 0.2f * se) + be;
            vv[nt][rr] = v;
            ss[rr] += v * v;
            int row = base + w * 16 + g16 * 4 + rr;
            if (row < NTOT) ego_out[(size_t)row * DDIM + nt * 16 + m] = f2bfu(v);
        }
    }
    #pragma unroll
    for (int rr = 0; rr < 4; ++rr) {
        ss[rr] += __shfl_xor(ss[rr], 1, 64);
        ss[rr] += __shfl_xor(ss[rr], 2, 64);
        ss[rr] += __shfl_xor(ss[rr], 4, 64);
        ss[rr] += __shfl_xor(ss[rr], 8, 64);
        ss[rr] = 1.f / fmaxf(sqrtf(ss[rr]), 1e-12f);
    }
    #pragma unroll
    for (int nt = 0; nt < 8; ++nt) {
        #pragma unroll
        for (int rr = 0; rr < 4; ++rr) {
            int row = base + w * 16 + g16 * 4 + rr;
            if (row < NTOT) normbuf[(size_t)row * DDIM + nt * 16 + m] = vv[nt][rr] * ss[rr];
        }
    }
}

// slot 0: gather raw ego rows EXACTLY from the fp32 inputs
__global__ void gather_ego_kernel(const float* __restrict__ feat, const float* __restrict__ user_emb,
                                  const float* __restrict__ item_emb1, const float* __restrict__ item_emb2,
                                  const int* __restrict__ users, const int* __restrict__ pos,
                                  const int* __restrict__ neg, float* __restrict__ out) {
    int i = blockIdx.x * 256 + threadIdx.x;  // exactly 3*NB*128 threads
    int which = i / (NB * DDIM);
    int rem = i - which * (NB * DDIM);
    int b = rem >> 7, d = rem & 127;
    float v;
    if (which == 0) {
        int u = users[b];
        v = (d < 64) ? user_emb[u*64 + d] : feat[u*64 + d - 64];
    } else {
        int m = (which == 1) ? pos[b] : neg[b];
        v = (d < 64) ? item_emb1[m*64 + d] : item_emb2[m*64 + d - 64];
    }
    out[(size_t)which * NB * 512 + (size_t)b * 512 + d] = v;
}

// slots 1..3: gather the 128-wide normalized slice from fp32 normbuf
__global__ void gather_slice_kernel(const float* __restrict__ src, const int* __restrict__ users,
                                    const int* __restrict__ pos, const int* __restrict__ neg,
                                    float* __restrict__ out, int slot) {
    int i = blockIdx.x * 256 + threadIdx.x;  // exactly 3*NB*128 threads
    int which = i / (NB * DDIM);
    int rem = i - which * (NB * DDIM);
    int b = rem >> 7, c = rem & 127;
    int row;
    if (which == 0)      row = users[b];
    else if (which == 1) row = N_USERS + pos[b];
    else                 row = N_USERS + neg[b];
    out[(size_t)which * NB * 512 + (size_t)b * 512 + slot * 128 + c] =
        src[(size_t)row * DDIM + c];
}

extern "C" void kernel_launch(void* const* d_in, const int* in_sizes, int n_in,
                              void* d_out, int out_size, void* d_ws, size_t ws_size,
                              hipStream_t stream) {
    (void)in_sizes; (void)n_in; (void)out_size; (void)ws_size;
    const int*   edge_row  = (const int*)  d_in[0];
    const int*   edge_col  = (const int*)  d_in[1];
    const float* edge_val  = (const float*)d_in[2];
    const float* feat      = (const float*)d_in[3];
    const float* user_emb  = (const float*)d_in[4];
    const float* item_emb1 = (const float*)d_in[5];
    const float* item_emb2 = (const float*)d_in[6];
    const float* alphas    = (const float*)d_in[7];
    const float* W_gc      = (const float*)d_in[8];
    const float* b_gc      = (const float*)d_in[9];
    const float* W_bi      = (const float*)d_in[10];
    const float* b_bi      = (const float*)d_in[11];
    const int*   users     = (const int*)  d_in[12];
    const int*   pos_items = (const int*)  d_in[13];
    const int*   neg_items = (const int*)  d_in[14];
    float* out = (float*)d_out;

    char* ws = (char*)d_ws;
    size_t off = 0;
    auto alloc = [&](size_t bytes) -> char* {
        char* p = ws + off;
        off = (off + bytes + 255) & ~(size_t)255;
        return p;
    };
    u16*   ego      = (u16*)  alloc((size_t)NTOT * DDIM * 2);   // 25.6 MB
    u16*   cur      = (u16*)  alloc((size_t)NTOT * DDIM * 2);   // 25.6 MB
    u16*   nxt      = (u16*)  alloc((size_t)NTOT * DDIM * 2);   // 25.6 MB
    float* side     = (float*)alloc((size_t)NTOT * DDIM * 4);   // 51.2 MB (also norm output)
    int*   rowptr   = (int*)  alloc((size_t)(NTOT + 1) * 4);
    int*   counts   = (int*)  alloc((size_t)NTOT * 4);
    int*   counters = (int*)  alloc((size_t)NTOT * 4);
    int*   bsums    = (int*)  alloc(4096);
    int*   csr_col  = (int*)  alloc((size_t)NEDGE * 4);         // 6.4 MB
    float* csr_val  = (float*)alloc((size_t)NEDGE * 4);         // 6.4 MB
    u16*   wtgc     = (u16*)  alloc((size_t)NLAY * DDIM * DDIM * 2);  // 96 KB
    u16*   wtbi     = (u16*)  alloc((size_t)NLAY * DDIM * DDIM * 2);  // 96 KB
    float* beta     = (float*)alloc(256);

    beta_kernel<<<1, 64, 0, stream>>>(alphas, beta);
    build_ego_kernel<<<(NTOT * DDIM) / 256, 256, 0, stream>>>(feat, user_emb, item_emb1, item_emb2, ego);
    transpose_w_kernel<<<dim3(4, 4, 6), dim3(32, 8), 0, stream>>>(W_gc, W_bi, wtgc, wtbi);

    zero_kernel<<<(NTOT + 255) / 256, 256, 0, stream>>>(counts, NTOT);
    hist_kernel<<<NEDGE / 256, 256, 0, stream>>>(edge_row, counts);
    int nblk = (NTOT + SCAN_BS - 1) / SCAN_BS;
    scan1_kernel<<<nblk, SCAN_BS, 0, stream>>>(counts, rowptr, bsums, NTOT);
    scan2_kernel<<<1, 64, 0, stream>>>(bsums, nblk);
    scan3_kernel<<<nblk, SCAN_BS, 0, stream>>>(rowptr, bsums, NTOT);
    copy_kernel<<<(NTOT + 255) / 256, 256, 0, stream>>>(rowptr, counters, NTOT);
    scatter_kernel<<<NEDGE / 256, 256, 0, stream>>>(edge_row, edge_col, edge_val, counters, csr_col, csr_val);

    // slot 0 of the output: raw ego rows, exact fp32
    gather_ego_kernel<<<(3 * NB * DDIM) / 256, 256, 0, stream>>>(feat, user_emb, item_emb1, item_emb2,
                                                                 users, pos_items, neg_items, out);

    int lgrid = (NTOT + LBM - 1) / LBM;   // 782
    for (int k = 0; k < NLAY; ++k) {
        spmm_kernel<<<NTOT / 16, 256, 0, stream>>>(rowptr, csr_col, csr_val, ego, cur, side, beta, k * KHOP + 0, 1);
        spmm_kernel<<<NTOT / 16, 256, 0, stream>>>(rowptr, csr_col, csr_val, cur, nxt, side, beta, k * KHOP + 1, 0);
        spmm_kernel<<<NTOT / 16, 256, 0, stream>>>(rowptr, csr_col, csr_val, nxt, cur, side, beta, k * KHOP + 2, 0);
        layer_kernel<<<lgrid, 512, 0, stream>>>(ego, side,
                                                wtgc + (size_t)k * DDIM * DDIM, wtbi + (size_t)k * DDIM * DDIM,
                                                b_gc + (size_t)k * DDIM, b_bi + (size_t)k * DDIM,
                                                ego, side);
        gather_slice_kernel<<<(3 * NB * DDIM) / 256, 256, 0, stream>>>(side, users, pos_items, neg_items, out, k + 1);
    }
}

// Round 5
// 1049.433 us; speedup vs baseline: 3.6791x; 1.0593x over previous
//
#include <hip/hip_runtime.h>
#include <hip/hip_bf16.h>

typedef __hip_bfloat16 hbf16;
typedef unsigned short u16;
typedef __bf16 bf16x8 __attribute__((ext_vector_type(8)));
typedef float f32x4 __attribute__((ext_vector_type(4)));

#define N_USERS 80000
#define N_ITEMS 20000
#define NTOT    100000
#define NEDGE   1600000
#define DDIM    128
#define NLAY    3
#define KHOP    3
#define NB      4096
#define SCAN_BS 1024
#define LBM     128   // rows per layer block

__device__ inline u16 f2bfu(float f) { __bf16 h = (__bf16)f; return __builtin_bit_cast(u16, h); }

__global__ void beta_kernel(const float* __restrict__ alphas, float* __restrict__ beta) {
    if (threadIdx.x == 0 && blockIdx.x == 0) {
        for (int k = 0; k < NLAY; ++k) {
            float a[KHOP];
            float m = -1e30f;
            for (int i = 0; i < KHOP; ++i) { a[i] = alphas[k*KHOP+i]; m = fmaxf(m, a[i]); }
            float s = 0.f;
            for (int i = 0; i < KHOP; ++i) { a[i] = expf(a[i] - m); s += a[i]; }
            for (int i = 0; i < KHOP; ++i) beta[k*KHOP+i] = a[i] / s;
        }
    }
}

__global__ void build_ego_kernel(const float* __restrict__ feat, const float* __restrict__ user_emb,
                                 const float* __restrict__ item_emb1, const float* __restrict__ item_emb2,
                                 u16* __restrict__ ego) {
    int i = blockIdx.x * 256 + threadIdx.x;   // exactly NTOT*DDIM threads
    int n = i >> 7, d = i & 127;
    float v;
    if (n < N_USERS) {
        v = (d < 64) ? user_emb[n*64 + d] : feat[n*64 + d - 64];
    } else {
        int m = n - N_USERS;
        v = (d < 64) ? item_emb1[m*64 + d] : item_emb2[m*64 + d - 64];
    }
    ego[i] = f2bfu(v);
}

// transpose 6 128x128 fp32 matrices into bf16 (WT[n][k] = W[k][n])
__global__ void transpose_w_kernel(const float* __restrict__ Wgc, const float* __restrict__ Wbi,
                                   u16* __restrict__ WTgc, u16* __restrict__ WTbi) {
    __shared__ float t[32][33];
    int z = blockIdx.z;
    const float* W = (z < 3) ? (Wgc + (size_t)z * 16384) : (Wbi + (size_t)(z - 3) * 16384);
    u16* WT = (z < 3) ? (WTgc + (size_t)z * 16384) : (WTbi + (size_t)(z - 3) * 16384);
    int r0 = blockIdx.y * 32, c0 = blockIdx.x * 32;
    for (int i = threadIdx.y; i < 32; i += 8)
        t[i][threadIdx.x] = W[(size_t)(r0 + i) * 128 + c0 + threadIdx.x];
    __syncthreads();
    for (int i = threadIdx.y; i < 32; i += 8)
        WT[(size_t)(c0 + i) * 128 + r0 + threadIdx.x] = f2bfu(t[threadIdx.x][i]);
}

__global__ void zero_kernel(int* __restrict__ p, int n) {
    int i = blockIdx.x * 256 + threadIdx.x;
    if (i < n) p[i] = 0;
}

__global__ void hist_kernel(const int* __restrict__ er, int* __restrict__ counts) {
    int i = blockIdx.x * 256 + threadIdx.x;
    if (i < NEDGE) atomicAdd(&counts[er[i]], 1);
}

__global__ void scan1_kernel(const int* __restrict__ counts, int* __restrict__ rowptr,
                             int* __restrict__ bsums, int n) {
    __shared__ int sm[SCAN_BS];
    int i = blockIdx.x * SCAN_BS + threadIdx.x;
    int v = (i < n) ? counts[i] : 0;
    sm[threadIdx.x] = v;
    __syncthreads();
    for (int off = 1; off < SCAN_BS; off <<= 1) {
        int t = (threadIdx.x >= off) ? sm[threadIdx.x - off] : 0;
        __syncthreads();
        sm[threadIdx.x] += t;
        __syncthreads();
    }
    if (i < n) rowptr[i] = sm[threadIdx.x] - v;  // exclusive
    if (threadIdx.x == SCAN_BS - 1) bsums[blockIdx.x] = sm[SCAN_BS - 1];
}

__global__ void scan2_kernel(int* __restrict__ bsums, int nb) {
    if (threadIdx.x == 0 && blockIdx.x == 0) {
        int acc = 0;
        for (int b = 0; b < nb; ++b) { int t = bsums[b]; bsums[b] = acc; acc += t; }
    }
}

__global__ void scan3_kernel(int* __restrict__ rowptr, const int* __restrict__ bsums, int n) {
    int i = blockIdx.x * SCAN_BS + threadIdx.x;
    if (i < n) rowptr[i] += bsums[blockIdx.x];
    if (blockIdx.x == 0 && threadIdx.x == 0) rowptr[n] = NEDGE;
}

__global__ void copy_kernel(const int* __restrict__ src, int* __restrict__ dst, int n) {
    int i = blockIdx.x * 256 + threadIdx.x;
    if (i < n) dst[i] = src[i];
}

// packed 8B edge record: {col, val_bits}
__global__ void scatter_kernel(const int* __restrict__ er, const int* __restrict__ ec,
                               const float* __restrict__ ev, int* __restrict__ counters,
                               int2* __restrict__ edges) {
    int i = blockIdx.x * 256 + threadIdx.x;
    if (i < NEDGE) {
        int r = er[i];
        int p = atomicAdd(&counters[r], 1);
        int2 rec;
        rec.x = ec[i];
        rec.y = __float_as_int(ev[i]);
        edges[p] = rec;
    }
}

// 16 lanes per row, 16 rows per 256-thread block; each lane owns 8 columns (16B loads)
// pure Y = A*X (beta-combination deferred to layer_kernel)
__global__ __launch_bounds__(256) void spmm_kernel(
    const int* __restrict__ rowptr, const int2* __restrict__ edges,
    const u16* __restrict__ X, u16* __restrict__ Y) {
    int tid = threadIdx.x;
    int r = blockIdx.x * 16 + (tid >> 4);
    int lane = tid & 15;
    int s = rowptr[r], e = rowptr[r + 1];
    float acc[8];
    #pragma unroll
    for (int i = 0; i < 8; ++i) acc[i] = 0.f;
    const u16* xb = X + lane * 8;
    for (int j = s; j < e; ++j) {
        int2 ed = edges[j];
        float v = __int_as_float(ed.y);
        bf16x8 x = *reinterpret_cast<const bf16x8*>(xb + (size_t)ed.x * DDIM);
        #pragma unroll
        for (int i = 0; i < 8; ++i) acc[i] = fmaf(v, (float)x[i], acc[i]);
    }
    size_t oi = (size_t)r * DDIM + lane * 8;
    bf16x8 y;
    #pragma unroll
    for (int i = 0; i < 8; ++i) y[i] = (__bf16)acc[i];
    *reinterpret_cast<bf16x8*>(Y + oi) = y;
}

// MFMA layer: 512 threads = 8 waves, 128 rows/block.
// Stages As = bf16(beta0 h1 + beta1 h2 + beta2 h3), Ab = bf16(side*ego) in swizzled LDS.
__global__ __launch_bounds__(512) void layer_kernel(
    const u16* __restrict__ ego, const u16* __restrict__ h1,
    const u16* __restrict__ h2, const u16* __restrict__ h3,
    const float* __restrict__ beta3,
    const u16* __restrict__ wtgc, const u16* __restrict__ wtbi,
    const float* __restrict__ bgc, const float* __restrict__ bbi,
    u16* __restrict__ ego_out, u16* __restrict__ normbuf) {
    __shared__ __align__(16) unsigned char smem[131072];
    const int AS = 0, AB = 32768, WG = 65536, WB = 98304;
    int tid = threadIdx.x;
    int base = blockIdx.x * LBM;
    float b0 = beta3[0], b1 = beta3[1], b2 = beta3[2];

    // stage A-tiles, rows of 256B, byte ^= (row&7)<<4
    {
        int row = tid >> 2, q = tid & 3;
        int grow = base + row;
        bool ok = grow < NTOT;
        size_t roff = (size_t)grow * DDIM + q * 32;
        int sw = (row & 7) << 4;
        #pragma unroll
        for (int cg = 0; cg < 4; ++cg) {
            bf16x8 pa, pb;
            if (ok) {
                bf16x8 x1 = *reinterpret_cast<const bf16x8*>(h1 + roff + cg * 8);
                bf16x8 x2 = *reinterpret_cast<const bf16x8*>(h2 + roff + cg * 8);
                bf16x8 x3 = *reinterpret_cast<const bf16x8*>(h3 + roff + cg * 8);
                bf16x8 ev = *reinterpret_cast<const bf16x8*>(ego + roff + cg * 8);
                #pragma unroll
                for (int i = 0; i < 8; ++i) {
                    float sf = b0 * (float)x1[i] + b1 * (float)x2[i] + b2 * (float)x3[i];
                    pa[i] = (__bf16)sf;
                    pb[i] = (__bf16)(sf * (float)ev[i]);
                }
            } else {
                #pragma unroll
                for (int i = 0; i < 8; ++i) { pa[i] = (__bf16)0.f; pb[i] = (__bf16)0.f; }
            }
            int kb = q * 64 + cg * 16;
            *reinterpret_cast<bf16x8*>(&smem[AS + row * 256 + (kb ^ sw)]) = pa;
            *reinterpret_cast<bf16x8*>(&smem[AB + row * 256 + (kb ^ sw)]) = pb;
        }
    }
    // stage pre-transposed W (bf16): WT[n][k], same swizzle
    #pragma unroll
    for (int p = 0; p < 4; ++p) {
        int slot = tid + p * 512;            // 2048 16B slots
        int n = slot >> 4, ks = slot & 15;
        uint4 g  = *reinterpret_cast<const uint4*>(wtgc + n * DDIM + ks * 8);
        uint4 bq = *reinterpret_cast<const uint4*>(wtbi + n * DDIM + ks * 8);
        int addr = n * 256 + ((ks * 16) ^ ((n & 7) << 4));
        *reinterpret_cast<uint4*>(&smem[WG + addr]) = g;
        *reinterpret_cast<uint4*>(&smem[WB + addr]) = bq;
    }
    __syncthreads();

    int l = tid & 63, w = tid >> 6;
    int m = l & 15, g16 = l >> 4;
    int sw = (m & 7) << 4;
    int arow = (w * 16 + m) * 256;
    f32x4 accg[8], accb[8];
    #pragma unroll
    for (int nt = 0; nt < 8; ++nt) {
        accg[nt] = (f32x4){0.f, 0.f, 0.f, 0.f};
        accb[nt] = (f32x4){0.f, 0.f, 0.f, 0.f};
    }
    #pragma unroll
    for (int kk = 0; kk < 4; ++kk) {
        int ka = (kk * 64 + g16 * 16) ^ sw;
        bf16x8 as = *reinterpret_cast<const bf16x8*>(&smem[AS + arow + ka]);
        bf16x8 ab = *reinterpret_cast<const bf16x8*>(&smem[AB + arow + ka]);
        #pragma unroll
        for (int nt = 0; nt < 8; ++nt) {
            int na = (nt * 16 + m) * 256 + ka;
            bf16x8 bg = *reinterpret_cast<const bf16x8*>(&smem[WG + na]);
            accg[nt] = __builtin_amdgcn_mfma_f32_16x16x32_bf16(as, bg, accg[nt], 0, 0, 0);
            bf16x8 bb = *reinterpret_cast<const bf16x8*>(&smem[WB + na]);
            accb[nt] = __builtin_amdgcn_mfma_f32_16x16x32_bf16(ab, bb, accb[nt], 0, 0, 0);
        }
    }
    // epilogue: bias + leaky + bilinear add, row-norm via 16-lane shfl reduce
    float bgv[8], bbv[8];
    #pragma unroll
    for (int nt = 0; nt < 8; ++nt) { bgv[nt] = bgc[nt * 16 + m]; bbv[nt] = bbi[nt * 16 + m]; }
    float vv[8][4];
    float ss[4] = {0.f, 0.f, 0.f, 0.f};
    #pragma unroll
    for (int nt = 0; nt < 8; ++nt) {
        #pragma unroll
        for (int rr = 0; rr < 4; ++rr) {
            float se = accg[nt][rr] + bgv[nt];
            float be = accb[nt][rr] + bbv[nt];
            float v = (se > 0.f ? se : 0.2f * se) + be;
            vv[nt][rr] = v;
            ss[rr] += v * v;
            int row = base + w * 16 + g16 * 4 + rr;
            if (row < NTOT) ego_out[(size_t)row * DDIM + nt * 16 + m] = f2bfu(v);
        }
    }
    #pragma unroll
    for (int rr = 0; rr < 4; ++rr) {
        ss[rr] += __shfl_xor(ss[rr], 1, 64);
        ss[rr] += __shfl_xor(ss[rr], 2, 64);
        ss[rr] += __shfl_xor(ss[rr], 4, 64);
        ss[rr] += __shfl_xor(ss[rr], 8, 64);
        ss[rr] = 1.f / fmaxf(sqrtf(ss[rr]), 1e-12f);
    }
    #pragma unroll
    for (int nt = 0; nt < 8; ++nt) {
        #pragma unroll
        for (int rr = 0; rr < 4; ++rr) {
            int row = base + w * 16 + g16 * 4 + rr;
            if (row < NTOT) normbuf[(size_t)row * DDIM + nt * 16 + m] = f2bfu(vv[nt][rr] * ss[rr]);
        }
    }
}

// slot 0: gather raw ego rows EXACTLY from the fp32 inputs
__global__ void gather_ego_kernel(const float* __restrict__ feat, const float* __restrict__ user_emb,
                                  const float* __restrict__ item_emb1, const float* __restrict__ item_emb2,
                                  const int* __restrict__ users, const int* __restrict__ pos,
                                  const int* __restrict__ neg, float* __restrict__ out) {
    int i = blockIdx.x * 256 + threadIdx.x;  // exactly 3*NB*128 threads
    int which = i / (NB * DDIM);
    int rem = i - which * (NB * DDIM);
    int b = rem >> 7, d = rem & 127;
    float v;
    if (which == 0) {
        int u = users[b];
        v = (d < 64) ? user_emb[u*64 + d] : feat[u*64 + d - 64];
    } else {
        int m = (which == 1) ? pos[b] : neg[b];
        v = (d < 64) ? item_emb1[m*64 + d] : item_emb2[m*64 + d - 64];
    }
    out[(size_t)which * NB * 512 + (size_t)b * 512 + d] = v;
}

// slots 1..3: gather the 128-wide normalized slice from bf16 normbuf
__global__ void gather_slice_kernel(const u16* __restrict__ src, const int* __restrict__ users,
                                    const int* __restrict__ pos, const int* __restrict__ neg,
                                    float* __restrict__ out, int slot) {
    int i = blockIdx.x * 256 + threadIdx.x;  // exactly 3*NB*128 threads
    int which = i / (NB * DDIM);
    int rem = i - which * (NB * DDIM);
    int b = rem >> 7, c = rem & 127;
    int row;
    if (which == 0)      row = users[b];
    else if (which == 1) row = N_USERS + pos[b];
    else                 row = N_USERS + neg[b];
    unsigned int u = src[(size_t)row * DDIM + c];
    out[(size_t)which * NB * 512 + (size_t)b * 512 + slot * 128 + c] =
        __builtin_bit_cast(float, u << 16);
}

extern "C" void kernel_launch(void* const* d_in, const int* in_sizes, int n_in,
                              void* d_out, int out_size, void* d_ws, size_t ws_size,
                              hipStream_t stream) {
    (void)in_sizes; (void)n_in; (void)out_size; (void)ws_size;
    const int*   edge_row  = (const int*)  d_in[0];
    const int*   edge_col  = (const int*)  d_in[1];
    const float* edge_val  = (const float*)d_in[2];
    const float* feat      = (const float*)d_in[3];
    const float* user_emb  = (const float*)d_in[4];
    const float* item_emb1 = (const float*)d_in[5];
    const float* item_emb2 = (const float*)d_in[6];
    const float* alphas    = (const float*)d_in[7];
    const float* W_gc      = (const float*)d_in[8];
    const float* b_gc      = (const float*)d_in[9];
    const float* W_bi      = (const float*)d_in[10];
    const float* b_bi      = (const float*)d_in[11];
    const int*   users     = (const int*)  d_in[12];
    const int*   pos_items = (const int*)  d_in[13];
    const int*   neg_items = (const int*)  d_in[14];
    float* out = (float*)d_out;

    char* ws = (char*)d_ws;
    size_t off = 0;
    auto alloc = [&](size_t bytes) -> char* {
        char* p = ws + off;
        off = (off + bytes + 255) & ~(size_t)255;
        return p;
    };
    // total ~142 MB (same as round 4, which ran fine)
    u16*   ego      = (u16*)  alloc((size_t)NTOT * DDIM * 2);   // 25.6 MB
    u16*   h1       = (u16*)  alloc((size_t)NTOT * DDIM * 2);   // 25.6 MB
    u16*   h2       = (u16*)  alloc((size_t)NTOT * DDIM * 2);   // 25.6 MB
    u16*   h3       = (u16*)  alloc((size_t)NTOT * DDIM * 2);   // 25.6 MB
    u16*   normbuf  = (u16*)  alloc((size_t)NTOT * DDIM * 2);   // 25.6 MB
    int*   rowptr   = (int*)  alloc((size_t)(NTOT + 1) * 4);
    int*   counts   = (int*)  alloc((size_t)NTOT * 4);
    int*   counters = (int*)  alloc((size_t)NTOT * 4);
    int*   bsums    = (int*)  alloc(4096);
    int2*  edges    = (int2*) alloc((size_t)NEDGE * 8);         // 12.8 MB
    u16*   wtgc     = (u16*)  alloc((size_t)NLAY * DDIM * DDIM * 2);  // 96 KB
    u16*   wtbi     = (u16*)  alloc((size_t)NLAY * DDIM * DDIM * 2);  // 96 KB
    float* beta     = (float*)alloc(256);

    beta_kernel<<<1, 64, 0, stream>>>(alphas, beta);
    build_ego_kernel<<<(NTOT * DDIM) / 256, 256, 0, stream>>>(feat, user_emb, item_emb1, item_emb2, ego);
    transpose_w_kernel<<<dim3(4, 4, 6), dim3(32, 8), 0, stream>>>(W_gc, W_bi, wtgc, wtbi);

    zero_kernel<<<(NTOT + 255) / 256, 256, 0, stream>>>(counts, NTOT);
    hist_kernel<<<NEDGE / 256, 256, 0, stream>>>(edge_row, counts);
    int nblk = (NTOT + SCAN_BS - 1) / SCAN_BS;
    scan1_kernel<<<nblk, SCAN_BS, 0, stream>>>(counts, rowptr, bsums, NTOT);
    scan2_kernel<<<1, 64, 0, stream>>>(bsums, nblk);
    scan3_kernel<<<nblk, SCAN_BS, 0, stream>>>(rowptr, bsums, NTOT);
    copy_kernel<<<(NTOT + 255) / 256, 256, 0, stream>>>(rowptr, counters, NTOT);
    scatter_kernel<<<NEDGE / 256, 256, 0, stream>>>(edge_row, edge_col, edge_val, counters, edges);

    // slot 0 of the output: raw ego rows, exact fp32
    gather_ego_kernel<<<(3 * NB * DDIM) / 256, 256, 0, stream>>>(feat, user_emb, item_emb1, item_emb2,
                                                                 users, pos_items, neg_items, out);

    int lgrid = (NTOT + LBM - 1) / LBM;   // 782
    for (int k = 0; k < NLAY; ++k) {
        spmm_kernel<<<NTOT / 16, 256, 0, stream>>>(rowptr, edges, ego, h1);
        spmm_kernel<<<NTOT / 16, 256, 0, stream>>>(rowptr, edges, h1, h2);
        spmm_kernel<<<NTOT / 16, 256, 0, stream>>>(rowptr, edges, h2, h3);
        layer_kernel<<<lgrid, 512, 0, stream>>>(ego, h1, h2, h3, beta + 3 * k,
                                                wtgc + (size_t)k * DDIM * DDIM, wtbi + (size_t)k * DDIM * DDIM,
                                                b_gc + (size_t)k * DDIM, b_bi + (size_t)k * DDIM,
                                                ego, normbuf);
        gather_slice_kernel<<<(3 * NB * DDIM) / 256, 256, 0, stream>>>(normbuf, users, pos_items, neg_items, out, k + 1);
    }
}

// Round 6
// 937.243 us; speedup vs baseline: 4.1195x; 1.1197x over previous
//
#include <hip/hip_runtime.h>
#include <hip/hip_bf16.h>

typedef __hip_bfloat16 hbf16;
typedef unsigned short u16;
typedef __bf16 bf16x8 __attribute__((ext_vector_type(8)));
typedef float f32x4 __attribute__((ext_vector_type(4)));

#define N_USERS 80000
#define N_ITEMS 20000
#define NTOT    100000
#define NEDGE   1600000
#define DDIM    128
#define NLAY    3
#define KHOP    3
#define NB      4096
#define SCAN_BS 1024
#define LBM     128   // rows per layer block

__device__ inline u16 f2bfu(float f) { __bf16 h = (__bf16)f; return __builtin_bit_cast(u16, h); }

__global__ void beta_kernel(const float* __restrict__ alphas, float* __restrict__ beta) {
    if (threadIdx.x == 0 && blockIdx.x == 0) {
        for (int k = 0; k < NLAY; ++k) {
            float a[KHOP];
            float m = -1e30f;
            for (int i = 0; i < KHOP; ++i) { a[i] = alphas[k*KHOP+i]; m = fmaxf(m, a[i]); }
            float s = 0.f;
            for (int i = 0; i < KHOP; ++i) { a[i] = expf(a[i] - m); s += a[i]; }
            for (int i = 0; i < KHOP; ++i) beta[k*KHOP+i] = a[i] / s;
        }
    }
}

__global__ void build_ego_kernel(const float* __restrict__ feat, const float* __restrict__ user_emb,
                                 const float* __restrict__ item_emb1, const float* __restrict__ item_emb2,
                                 u16* __restrict__ ego) {
    int i = blockIdx.x * 256 + threadIdx.x;   // exactly NTOT*DDIM threads
    int n = i >> 7, d = i & 127;
    float v;
    if (n < N_USERS) {
        v = (d < 64) ? user_emb[n*64 + d] : feat[n*64 + d - 64];
    } else {
        int m = n - N_USERS;
        v = (d < 64) ? item_emb1[m*64 + d] : item_emb2[m*64 + d - 64];
    }
    ego[i] = f2bfu(v);
}

// transpose 6 128x128 fp32 matrices into bf16 (WT[n][k] = W[k][n])
__global__ void transpose_w_kernel(const float* __restrict__ Wgc, const float* __restrict__ Wbi,
                                   u16* __restrict__ WTgc, u16* __restrict__ WTbi) {
    __shared__ float t[32][33];
    int z = blockIdx.z;
    const float* W = (z < 3) ? (Wgc + (size_t)z * 16384) : (Wbi + (size_t)(z - 3) * 16384);
    u16* WT = (z < 3) ? (WTgc + (size_t)z * 16384) : (WTbi + (size_t)(z - 3) * 16384);
    int r0 = blockIdx.y * 32, c0 = blockIdx.x * 32;
    for (int i = threadIdx.y; i < 32; i += 8)
        t[i][threadIdx.x] = W[(size_t)(r0 + i) * 128 + c0 + threadIdx.x];
    __syncthreads();
    for (int i = threadIdx.y; i < 32; i += 8)
        WT[(size_t)(c0 + i) * 128 + r0 + threadIdx.x] = f2bfu(t[threadIdx.x][i]);
}

__global__ void zero_kernel(int* __restrict__ p, int n) {
    int i = blockIdx.x * 256 + threadIdx.x;
    if (i < n) p[i] = 0;
}

__global__ void hist_kernel(const int* __restrict__ er, int* __restrict__ counts) {
    int i = blockIdx.x * 256 + threadIdx.x;
    if (i < NEDGE) atomicAdd(&counts[er[i]], 1);
}

__global__ void scan1_kernel(const int* __restrict__ counts, int* __restrict__ rowptr,
                             int* __restrict__ bsums, int n) {
    __shared__ int sm[SCAN_BS];
    int i = blockIdx.x * SCAN_BS + threadIdx.x;
    int v = (i < n) ? counts[i] : 0;
    sm[threadIdx.x] = v;
    __syncthreads();
    for (int off = 1; off < SCAN_BS; off <<= 1) {
        int t = (threadIdx.x >= off) ? sm[threadIdx.x - off] : 0;
        __syncthreads();
        sm[threadIdx.x] += t;
        __syncthreads();
    }
    if (i < n) rowptr[i] = sm[threadIdx.x] - v;  // exclusive
    if (threadIdx.x == SCAN_BS - 1) bsums[blockIdx.x] = sm[SCAN_BS - 1];
}

__global__ void scan2_kernel(int* __restrict__ bsums, int nb) {
    if (threadIdx.x == 0 && blockIdx.x == 0) {
        int acc = 0;
        for (int b = 0; b < nb; ++b) { int t = bsums[b]; bsums[b] = acc; acc += t; }
    }
}

// finalize rowptr AND seed the scatter counters (merged old copy_kernel)
__global__ void scan3_kernel(int* __restrict__ rowptr, const int* __restrict__ bsums,
                             int* __restrict__ counters, int n) {
    int i = blockIdx.x * SCAN_BS + threadIdx.x;
    if (i < n) {
        int v = rowptr[i] + bsums[blockIdx.x];
        rowptr[i] = v;
        counters[i] = v;
    }
    if (blockIdx.x == 0 && threadIdx.x == 0) rowptr[n] = NEDGE;
}

// packed 8B edge record {col, val_bits}; nontemporal store avoids cross-XCD L2 line bouncing
__global__ void scatter_kernel(const int* __restrict__ er, const int* __restrict__ ec,
                               const float* __restrict__ ev, int* __restrict__ counters,
                               int2* __restrict__ edges) {
    int i = blockIdx.x * 256 + threadIdx.x;
    if (i < NEDGE) {
        int r = er[i];
        int p = atomicAdd(&counters[r], 1);
        unsigned long long rec = ((unsigned long long)(unsigned)__float_as_int(ev[i]) << 32)
                               | (unsigned)ec[i];
        __builtin_nontemporal_store(rec, reinterpret_cast<unsigned long long*>(edges + p));
    }
}

// 16 lanes per row, 16 rows per 256-thread block; each lane owns 8 columns (16B loads).
// Edge loop unrolled x4: 4 independent X-gathers in flight per lane.
__global__ __launch_bounds__(256) void spmm_kernel(
    const int* __restrict__ rowptr, const int2* __restrict__ edges,
    const u16* __restrict__ X, u16* __restrict__ Y) {
    int tid = threadIdx.x;
    int r = blockIdx.x * 16 + (tid >> 4);
    int lane = tid & 15;
    int s = rowptr[r], e = rowptr[r + 1];
    float acc[8];
    #pragma unroll
    for (int i = 0; i < 8; ++i) acc[i] = 0.f;
    const u16* xb = X + lane * 8;
    int j = s;
    for (; j + 4 <= e; j += 4) {
        int2 e0 = edges[j+0], e1 = edges[j+1], e2 = edges[j+2], e3 = edges[j+3];
        bf16x8 x0 = *reinterpret_cast<const bf16x8*>(xb + (size_t)e0.x * DDIM);
        bf16x8 x1 = *reinterpret_cast<const bf16x8*>(xb + (size_t)e1.x * DDIM);
        bf16x8 x2 = *reinterpret_cast<const bf16x8*>(xb + (size_t)e2.x * DDIM);
        bf16x8 x3 = *reinterpret_cast<const bf16x8*>(xb + (size_t)e3.x * DDIM);
        float v0 = __int_as_float(e0.y), v1 = __int_as_float(e1.y);
        float v2 = __int_as_float(e2.y), v3 = __int_as_float(e3.y);
        #pragma unroll
        for (int i = 0; i < 8; ++i) acc[i] = fmaf(v0, (float)x0[i], acc[i]);
        #pragma unroll
        for (int i = 0; i < 8; ++i) acc[i] = fmaf(v1, (float)x1[i], acc[i]);
        #pragma unroll
        for (int i = 0; i < 8; ++i) acc[i] = fmaf(v2, (float)x2[i], acc[i]);
        #pragma unroll
        for (int i = 0; i < 8; ++i) acc[i] = fmaf(v3, (float)x3[i], acc[i]);
    }
    for (; j < e; ++j) {
        int2 ed = edges[j];
        float v = __int_as_float(ed.y);
        bf16x8 x = *reinterpret_cast<const bf16x8*>(xb + (size_t)ed.x * DDIM);
        #pragma unroll
        for (int i = 0; i < 8; ++i) acc[i] = fmaf(v, (float)x[i], acc[i]);
    }
    size_t oi = (size_t)r * DDIM + lane * 8;
    bf16x8 y;
    #pragma unroll
    for (int i = 0; i < 8; ++i) y[i] = (__bf16)acc[i];
    *reinterpret_cast<bf16x8*>(Y + oi) = y;
}

// MFMA layer: 512 threads = 8 waves, 128 rows/block.
// Stages As = bf16(beta0 h1 + beta1 h2 + beta2 h3), Ab = bf16(side*ego) in swizzled LDS.
__global__ __launch_bounds__(512) void layer_kernel(
    const u16* __restrict__ ego, const u16* __restrict__ h1,
    const u16* __restrict__ h2, const u16* __restrict__ h3,
    const float* __restrict__ beta3,
    const u16* __restrict__ wtgc, const u16* __restrict__ wtbi,
    const float* __restrict__ bgc, const float* __restrict__ bbi,
    u16* __restrict__ ego_out, u16* __restrict__ normbuf) {
    __shared__ __align__(16) unsigned char smem[131072];
    const int AS = 0, AB = 32768, WG = 65536, WB = 98304;
    int tid = threadIdx.x;
    int base = blockIdx.x * LBM;
    float b0 = beta3[0], b1 = beta3[1], b2 = beta3[2];

    // stage A-tiles, rows of 256B, byte ^= (row&7)<<4
    {
        int row = tid >> 2, q = tid & 3;
        int grow = base + row;
        bool ok = grow < NTOT;
        size_t roff = (size_t)grow * DDIM + q * 32;
        int sw = (row & 7) << 4;
        #pragma unroll
        for (int cg = 0; cg < 4; ++cg) {
            bf16x8 pa, pb;
            if (ok) {
                bf16x8 x1 = *reinterpret_cast<const bf16x8*>(h1 + roff + cg * 8);
                bf16x8 x2 = *reinterpret_cast<const bf16x8*>(h2 + roff + cg * 8);
                bf16x8 x3 = *reinterpret_cast<const bf16x8*>(h3 + roff + cg * 8);
                bf16x8 ev = *reinterpret_cast<const bf16x8*>(ego + roff + cg * 8);
                #pragma unroll
                for (int i = 0; i < 8; ++i) {
                    float sf = b0 * (float)x1[i] + b1 * (float)x2[i] + b2 * (float)x3[i];
                    pa[i] = (__bf16)sf;
                    pb[i] = (__bf16)(sf * (float)ev[i]);
                }
            } else {
                #pragma unroll
                for (int i = 0; i < 8; ++i) { pa[i] = (__bf16)0.f; pb[i] = (__bf16)0.f; }
            }
            int kb = q * 64 + cg * 16;
            *reinterpret_cast<bf16x8*>(&smem[AS + row * 256 + (kb ^ sw)]) = pa;
            *reinterpret_cast<bf16x8*>(&smem[AB + row * 256 + (kb ^ sw)]) = pb;
        }
    }
    // stage pre-transposed W (bf16): WT[n][k], same swizzle
    #pragma unroll
    for (int p = 0; p < 4; ++p) {
        int slot = tid + p * 512;            // 2048 16B slots
        int n = slot >> 4, ks = slot & 15;
        uint4 g  = *reinterpret_cast<const uint4*>(wtgc + n * DDIM + ks * 8);
        uint4 bq = *reinterpret_cast<const uint4*>(wtbi + n * DDIM + ks * 8);
        int addr = n * 256 + ((ks * 16) ^ ((n & 7) << 4));
        *reinterpret_cast<uint4*>(&smem[WG + addr]) = g;
        *reinterpret_cast<uint4*>(&smem[WB + addr]) = bq;
    }
    __syncthreads();

    int l = tid & 63, w = tid >> 6;
    int m = l & 15, g16 = l >> 4;
    int sw = (m & 7) << 4;
    int arow = (w * 16 + m) * 256;
    f32x4 accg[8], accb[8];
    #pragma unroll
    for (int nt = 0; nt < 8; ++nt) {
        accg[nt] = (f32x4){0.f, 0.f, 0.f, 0.f};
        accb[nt] = (f32x4){0.f, 0.f, 0.f, 0.f};
    }
    #pragma unroll
    for (int kk = 0; kk < 4; ++kk) {
        int ka = (kk * 64 + g16 * 16) ^ sw;
        bf16x8 as = *reinterpret_cast<const bf16x8*>(&smem[AS + arow + ka]);
        bf16x8 ab = *reinterpret_cast<const bf16x8*>(&smem[AB + arow + ka]);
        #pragma unroll
        for (int nt = 0; nt < 8; ++nt) {
            int na = (nt * 16 + m) * 256 + ka;
            bf16x8 bg = *reinterpret_cast<const bf16x8*>(&smem[WG + na]);
            accg[nt] = __builtin_amdgcn_mfma_f32_16x16x32_bf16(as, bg, accg[nt], 0, 0, 0);
            bf16x8 bb = *reinterpret_cast<const bf16x8*>(&smem[WB + na]);
            accb[nt] = __builtin_amdgcn_mfma_f32_16x16x32_bf16(ab, bb, accb[nt], 0, 0, 0);
        }
    }
    // epilogue: bias + leaky + bilinear add, row-norm via 16-lane shfl reduce
    float bgv[8], bbv[8];
    #pragma unroll
    for (int nt = 0; nt < 8; ++nt) { bgv[nt] = bgc[nt * 16 + m]; bbv[nt] = bbi[nt * 16 + m]; }
    float vv[8][4];
    float ss[4] = {0.f, 0.f, 0.f, 0.f};
    #pragma unroll
    for (int nt = 0; nt < 8; ++nt) {
        #pragma unroll
        for (int rr = 0; rr < 4; ++rr) {
            float se = accg[nt][rr] + bgv[nt];
            float be = accb[nt][rr] + bbv[nt];
            float v = (se > 0.f ? se : 0.2f * se) + be;
            vv[nt][rr] = v;
            ss[rr] += v * v;
            int row = base + w * 16 + g16 * 4 + rr;
            if (row < NTOT) ego_out[(size_t)row * DDIM + nt * 16 + m] = f2bfu(v);
        }
    }
    #pragma unroll
    for (int rr = 0; rr < 4; ++rr) {
        ss[rr] += __shfl_xor(ss[rr], 1, 64);
        ss[rr] += __shfl_xor(ss[rr], 2, 64);
        ss[rr] += __shfl_xor(ss[rr], 4, 64);
        ss[rr] += __shfl_xor(ss[rr], 8, 64);
        ss[rr] = 1.f / fmaxf(sqrtf(ss[rr]), 1e-12f);
    }
    #pragma unroll
    for (int nt = 0; nt < 8; ++nt) {
        #pragma unroll
        for (int rr = 0; rr < 4; ++rr) {
            int row = base + w * 16 + g16 * 4 + rr;
            if (row < NTOT) normbuf[(size_t)row * DDIM + nt * 16 + m] = f2bfu(vv[nt][rr] * ss[rr]);
        }
    }
}

// slot 0: gather raw ego rows EXACTLY from the fp32 inputs
__global__ void gather_ego_kernel(const float* __restrict__ feat, const float* __restrict__ user_emb,
                                  const float* __restrict__ item_emb1, const float* __restrict__ item_emb2,
                                  const int* __restrict__ users, const int* __restrict__ pos,
                                  const int* __restrict__ neg, float* __restrict__ out) {
    int i = blockIdx.x * 256 + threadIdx.x;  // exactly 3*NB*128 threads
    int which = i / (NB * DDIM);
    int rem = i - which * (NB * DDIM);
    int b = rem >> 7, d = rem & 127;
    float v;
    if (which == 0) {
        int u = users[b];
        v = (d < 64) ? user_emb[u*64 + d] : feat[u*64 + d - 64];
    } else {
        int m = (which == 1) ? pos[b] : neg[b];
        v = (d < 64) ? item_emb1[m*64 + d] : item_emb2[m*64 + d - 64];
    }
    out[(size_t)which * NB * 512 + (size_t)b * 512 + d] = v;
}

// slots 1..3: gather the 128-wide normalized slice from bf16 normbuf
__global__ void gather_slice_kernel(const u16* __restrict__ src, const int* __restrict__ users,
                                    const int* __restrict__ pos, const int* __restrict__ neg,
                                    float* __restrict__ out, int slot) {
    int i = blockIdx.x * 256 + threadIdx.x;  // exactly 3*NB*128 threads
    int which = i / (NB * DDIM);
    int rem = i - which * (NB * DDIM);
    int b = rem >> 7, c = rem & 127;
    int row;
    if (which == 0)      row = users[b];
    else if (which == 1) row = N_USERS + pos[b];
    else                 row = N_USERS + neg[b];
    unsigned int u = src[(size_t)row * DDIM + c];
    out[(size_t)which * NB * 512 + (size_t)b * 512 + slot * 128 + c] =
        __builtin_bit_cast(float, u << 16);
}

extern "C" void kernel_launch(void* const* d_in, const int* in_sizes, int n_in,
                              void* d_out, int out_size, void* d_ws, size_t ws_size,
                              hipStream_t stream) {
    (void)in_sizes; (void)n_in; (void)out_size; (void)ws_size;
    const int*   edge_row  = (const int*)  d_in[0];
    const int*   edge_col  = (const int*)  d_in[1];
    const float* edge_val  = (const float*)d_in[2];
    const float* feat      = (const float*)d_in[3];
    const float* user_emb  = (const float*)d_in[4];
    const float* item_emb1 = (const float*)d_in[5];
    const float* item_emb2 = (const float*)d_in[6];
    const float* alphas    = (const float*)d_in[7];
    const float* W_gc      = (const float*)d_in[8];
    const float* b_gc      = (const float*)d_in[9];
    const float* W_bi      = (const float*)d_in[10];
    const float* b_bi      = (const float*)d_in[11];
    const int*   users     = (const int*)  d_in[12];
    const int*   pos_items = (const int*)  d_in[13];
    const int*   neg_items = (const int*)  d_in[14];
    float* out = (float*)d_out;

    char* ws = (char*)d_ws;
    size_t off = 0;
    auto alloc = [&](size_t bytes) -> char* {
        char* p = ws + off;
        off = (off + bytes + 255) & ~(size_t)255;
        return p;
    };
    u16*   ego      = (u16*)  alloc((size_t)NTOT * DDIM * 2);   // 25.6 MB
    u16*   h1       = (u16*)  alloc((size_t)NTOT * DDIM * 2);   // 25.6 MB
    u16*   h2       = (u16*)  alloc((size_t)NTOT * DDIM * 2);   // 25.6 MB
    u16*   h3       = (u16*)  alloc((size_t)NTOT * DDIM * 2);   // 25.6 MB
    u16*   normbuf  = (u16*)  alloc((size_t)NTOT * DDIM * 2);   // 25.6 MB
    int*   rowptr   = (int*)  alloc((size_t)(NTOT + 1) * 4);
    int*   counts   = (int*)  alloc((size_t)NTOT * 4);
    int*   counters = (int*)  alloc((size_t)NTOT * 4);
    int*   bsums    = (int*)  alloc(4096);
    int2*  edges    = (int2*) alloc((size_t)NEDGE * 8);         // 12.8 MB
    u16*   wtgc     = (u16*)  alloc((size_t)NLAY * DDIM * DDIM * 2);  // 96 KB
    u16*   wtbi     = (u16*)  alloc((size_t)NLAY * DDIM * DDIM * 2);  // 96 KB
    float* beta     = (float*)alloc(256);

    beta_kernel<<<1, 64, 0, stream>>>(alphas, beta);
    build_ego_kernel<<<(NTOT * DDIM) / 256, 256, 0, stream>>>(feat, user_emb, item_emb1, item_emb2, ego);
    transpose_w_kernel<<<dim3(4, 4, 6), dim3(32, 8), 0, stream>>>(W_gc, W_bi, wtgc, wtbi);

    zero_kernel<<<(NTOT + 255) / 256, 256, 0, stream>>>(counts, NTOT);
    hist_kernel<<<NEDGE / 256, 256, 0, stream>>>(edge_row, counts);
    int nblk = (NTOT + SCAN_BS - 1) / SCAN_BS;
    scan1_kernel<<<nblk, SCAN_BS, 0, stream>>>(counts, rowptr, bsums, NTOT);
    scan2_kernel<<<1, 64, 0, stream>>>(bsums, nblk);
    scan3_kernel<<<nblk, SCAN_BS, 0, stream>>>(rowptr, bsums, counters, NTOT);
    scatter_kernel<<<NEDGE / 256, 256, 0, stream>>>(edge_row, edge_col, edge_val, counters, edges);

    // slot 0 of the output: raw ego rows, exact fp32
    gather_ego_kernel<<<(3 * NB * DDIM) / 256, 256, 0, stream>>>(feat, user_emb, item_emb1, item_emb2,
                                                                 users, pos_items, neg_items, out);

    int lgrid = (NTOT + LBM - 1) / LBM;   // 782
    for (int k = 0; k < NLAY; ++k) {
        spmm_kernel<<<NTOT / 16, 256, 0, stream>>>(rowptr, edges, ego, h1);
        spmm_kernel<<<NTOT / 16, 256, 0, stream>>>(rowptr, edges, h1, h2);
        spmm_kernel<<<NTOT / 16, 256, 0, stream>>>(rowptr, edges, h2, h3);
        layer_kernel<<<lgrid, 512, 0, stream>>>(ego, h1, h2, h3, beta + 3 * k,
                                                wtgc + (size_t)k * DDIM * DDIM, wtbi + (size_t)k * DDIM * DDIM,
                                                b_gc + (size_t)k * DDIM, b_bi + (size_t)k * DDIM,
                                                ego, normbuf);
        gather_slice_kernel<<<(3 * NB * DDIM) / 256, 256, 0, stream>>>(normbuf, users, pos_items, neg_items, out, k + 1);
    }
}